// Round 2
// baseline (227.628 us; speedup 1.0000x reference)
//
#include <hip/hip_runtime.h>
#include <hip/hip_bf16.h>

typedef unsigned short ushort_t;
typedef unsigned int uint_t;
using f32x4  = __attribute__((ext_vector_type(4))) float;
using short8 = __attribute__((ext_vector_type(8))) short;

#define NN 8192

__device__ __forceinline__ ushort_t f2bf(float f) {
  uint_t u = __builtin_bit_cast(uint_t, f);
  u += 0x7FFFu + ((u >> 16) & 1u);   // RNE
  return (ushort_t)(u >> 16);
}

// ---------------------------------------------------------------------------
// K1: Xp = X @ W  -> XpT bf16 [2*64][8192] (row = h*64+c), x0[N][2], x1T[2][N]
// block = 256 threads, 32 nodes/block. thread: pair p=c*2+h, node group g.
// ---------------------------------------------------------------------------
__global__ __launch_bounds__(256) void k1_project(
    const float* __restrict__ X, const float* __restrict__ W,
    const float* __restrict__ attn,
    ushort_t* __restrict__ XpT, float* __restrict__ x0g, float* __restrict__ x1g)
{
  __shared__ float    Xl[32][128];      // 16 KB
  __shared__ ushort_t XpL[128][56];     // 14 KB (56: 16B-aligned rows, bank-spread)
  __shared__ float    P0[128][33];      // 16.9 KB (+1 pad)
  __shared__ float    P1[128][33];
  const int t  = threadIdx.x;
  const int nb = blockIdx.x * 32;

  // stage X tile (contiguous 16 KB)
  #pragma unroll
  for (int r = 0; r < 4; ++r) {
    int chunk = r * 256 + t;
    ((float4*)(&Xl[0][0]))[chunk] = ((const float4*)(X + (size_t)nb * 128))[chunk];
  }
  __syncthreads();

  const int p = t & 127;      // (c,h) pair: W flat index j*128 + c*2 + h
  const int g = t >> 7;       // node half
  const int h = p & 1, c = p >> 1;

  float acc[16];
  #pragma unroll
  for (int n = 0; n < 16; ++n) acc[n] = 0.f;

  for (int jc = 0; jc < 4; ++jc) {
    float wreg[32];
    #pragma unroll
    for (int jj = 0; jj < 32; ++jj) wreg[jj] = W[(jc * 32 + jj) * 128 + p]; // coalesced per wave
    #pragma unroll
    for (int n = 0; n < 16; ++n) {
      const float4* xr = (const float4*)(&Xl[g * 16 + n][jc * 32]); // broadcast b128 reads
      float s = acc[n];
      #pragma unroll
      for (int q = 0; q < 8; ++q) {
        float4 xv = xr[q];
        s += xv.x * wreg[q*4+0] + xv.y * wreg[q*4+1] + xv.z * wreg[q*4+2] + xv.w * wreg[q*4+3];
      }
      acc[n] = s;
    }
  }

  const float a0 = attn[p];         // attn[c][h], first half  (flat = c*2+h = p)
  const float a1 = attn[128 + p];   // second half
  const int   row = h * 64 + c;
  #pragma unroll
  for (int n = 0; n < 16; ++n) {
    P0[p][g * 16 + n]  = acc[n] * a0;
    P1[p][g * 16 + n]  = acc[n] * a1;
    XpL[row][g * 16 + n] = f2bf(acc[n]);
  }
  __syncthreads();

  // coalesced-ish transpose store of XpT: FULL 32 nodes = 64 B per row
  if (t < 128) {
    ushort_t* dst = XpT + (size_t)t * NN + nb;
    const uint4* src = (const uint4*)(&XpL[t][0]);
    ((uint4*)dst)[0] = src[0];
    ((uint4*)dst)[1] = src[1];
    ((uint4*)dst)[2] = src[2];
    ((uint4*)dst)[3] = src[3];
  }
  // x0/x1 reductions over c (fp32)
  if (t < 64) {
    int node = t >> 1, hh = t & 1;
    float s0 = 0.f, s1 = 0.f;
    #pragma unroll
    for (int cc = 0; cc < 64; ++cc) {
      s0 += P0[cc * 2 + hh][node];
      s1 += P1[cc * 2 + hh][node];
    }
    x0g[(nb + node) * 2 + hh] = s0;
    x1g[hh * NN + nb + node]  = s1;
  }
}

// ---------------------------------------------------------------------------
// K2: one pass over A. P[i,k,h] = A[i,k]*exp(lrelu(x0[i,h]+x1[k,h])) -> bf16
// MFMA 16x16x32: part[i,h,c] += P · Xp ; den[i,h] += row-sum(P).
// BI=32 rows/block, BK=64, 4 waves (wave: head = w&1, rows = (w>>1)*16).
// k-split S across blocks; partials combined in K3.
// ---------------------------------------------------------------------------
__global__ __launch_bounds__(256) void k2_main(
    const float* __restrict__ A, const ushort_t* __restrict__ XpT,
    const float* __restrict__ x0g, const float* __restrict__ x1g,
    float* __restrict__ part, float* __restrict__ denp,
    const int S, const int KS)
{
  __shared__ __align__(16) ushort_t Pl[2 * 32 * 64];   // 8 KB, XOR-swizzled
  __shared__ __align__(16) ushort_t Bl[2 * 64 * 64];   // 16 KB, XOR-swizzled
  const int t  = threadIdx.x;
  const int b  = blockIdx.x;
  const int rb = b / S, sp = b % S;
  const int ib = rb * 32;
  const int k0 = sp * KS;
  const int lane = t & 63, w = t >> 6;
  const int hw = w & 1, iw = (w >> 1) * 16;   // wave's head / row block
  const int pr = t >> 4;                      // P-compute: row within pass
  const int pk = (t & 15) * 4;                // P-compute: k offset (4 floats)

  float x0a[2][2];
  #pragma unroll
  for (int ps = 0; ps < 2; ++ps) {
    float2 v = *(const float2*)(x0g + (ib + ps * 16 + pr) * 2);
    x0a[ps][0] = v.x; x0a[ps][1] = v.y;
  }

  f32x4 acc[4] = {};
  float den[2][2] = {};

  const float* Ar0 = A + (size_t)(ib + pr) * NN;
  const float* Ar1 = A + (size_t)(ib + 16 + pr) * NN;

  for (int kt = k0; kt < k0 + KS; kt += 64) {
    // --- global loads (HBM stream = A; x1/Xp are L2-resident) ---
    float4 av0 = *(const float4*)(Ar0 + kt + pk);
    float4 av1 = *(const float4*)(Ar1 + kt + pk);
    float4 xv0 = *(const float4*)(x1g + kt + pk);
    float4 xv1 = *(const float4*)(x1g + NN + kt + pk);

    uint4 bst[4];   // XpT tile 16 KB: 1024 chunks of 16B
    #pragma unroll
    for (int r = 0; r < 4; ++r) {
      int chunk = r * 256 + t;
      int cr = chunk >> 3, j = chunk & 7;
      bst[r] = *(const uint4*)(XpT + (size_t)cr * NN + kt + j * 8);
    }

    // --- compute P (VALU) ---
    float aarr[2][4] = {{av0.x, av0.y, av0.z, av0.w}, {av1.x, av1.y, av1.z, av1.w}};
    float xarr[2][4] = {{xv0.x, xv0.y, xv0.z, xv0.w}, {xv1.x, xv1.y, xv1.z, xv1.w}};
    uint_t pp[2][2][2];
    #pragma unroll
    for (int ps = 0; ps < 2; ++ps) {
      #pragma unroll
      for (int hh = 0; hh < 2; ++hh) {
        ushort_t bf[4];
        #pragma unroll
        for (int j = 0; j < 4; ++j) {
          float s   = x0a[ps][hh] + xarr[hh][j];
          float lrl = fmaxf(s, 0.2f * s);
          float e   = __expf(lrl);
          float pv  = aarr[ps][j] * e;
          den[ps][hh] += pv;
          bf[j] = f2bf(pv);
        }
        pp[ps][hh][0] = (uint_t)bf[0] | ((uint_t)bf[1] << 16);
        pp[ps][hh][1] = (uint_t)bf[2] | ((uint_t)bf[3] << 16);
      }
    }

    __syncthreads();   // prev-iter MFMA reads done

    // --- LDS writes (both swizzled: byte ^= (row&7)<<4) ---
    #pragma unroll
    for (int r = 0; r < 4; ++r) {
      int chunk = r * 256 + t;
      int cr = chunk >> 3;
      int dst = (chunk * 16) ^ ((cr & 7) << 4);
      *(uint4*)((char*)Bl + dst) = bst[r];
    }
    #pragma unroll
    for (int ps = 0; ps < 2; ++ps) {
      #pragma unroll
      for (int hh = 0; hh < 2; ++hh) {
        int row = hh * 32 + ps * 16 + pr;
        int dst = (row * 128 + pk * 2) ^ ((pr & 7) << 4);
        uint2 v; v.x = pp[ps][hh][0]; v.y = pp[ps][hh][1];
        *(uint2*)((char*)Pl + dst) = v;
      }
    }

    __syncthreads();   // tiles visible

    // --- MFMA: wave (hw, iw): 16 rows x 64 cols, K=64 ---
    #pragma unroll
    for (int ks = 0; ks < 2; ++ks) {
      const int arow = hw * 32 + iw + (lane & 15);
      const int aoff = (arow * 128 + ks * 64 + (lane >> 4) * 16) ^ (((lane & 15) & 7) << 4);
      short8 af = *(const short8*)((const char*)Pl + aoff);
      #pragma unroll
      for (int cb = 0; cb < 4; ++cb) {
        const int brow = hw * 64 + cb * 16 + (lane & 15);
        const int boff = (brow * 128 + ks * 64 + (lane >> 4) * 16) ^ (((lane & 15) & 7) << 4);
        short8 bv = *(const short8*)((const char*)Bl + boff);
        acc[cb] = __builtin_amdgcn_mfma_f32_16x16x32_bf16(af, bv, acc[cb], 0, 0, 0);
      }
    }
  }

  // --- den: reduce k-partials across 16-lane groups (same row) ---
  #pragma unroll
  for (int ps = 0; ps < 2; ++ps) {
    #pragma unroll
    for (int hh = 0; hh < 2; ++hh) {
      float d = den[ps][hh];
      d += __shfl_xor(d, 1, 16);
      d += __shfl_xor(d, 2, 16);
      d += __shfl_xor(d, 4, 16);
      d += __shfl_xor(d, 8, 16);
      if ((t & 15) == 0)
        denp[((size_t)sp * NN + ib + ps * 16 + (t >> 4)) * 2 + hh] = d;
    }
  }

  // --- write partial numerators (C/D layout: col=lane&15, row=(lane>>4)*4+r) ---
  float* pbase = part + ((size_t)sp * NN + ib) * 128;
  #pragma unroll
  for (int cb = 0; cb < 4; ++cb) {
    #pragma unroll
    for (int r = 0; r < 4; ++r) {
      int lr  = iw + (lane >> 4) * 4 + r;
      int col = cb * 16 + (lane & 15);
      pbase[lr * 128 + hw * 64 + col] = acc[cb][r];
    }
  }
}

// ---------------------------------------------------------------------------
// K3: combine splits, normalize by 1/(den+1e-3), add bias. out[i][h][c] fp32.
// ---------------------------------------------------------------------------
__global__ __launch_bounds__(256) void k3_finish(
    const float* __restrict__ part, const float* __restrict__ denp,
    const float* __restrict__ bias, float* __restrict__ out, const int S)
{
  const int idx = blockIdx.x * 256 + threadIdx.x;   // 0..262143 (float4 items)
  const int i  = idx >> 5;
  const int hc = (idx & 31) * 4;
  const int h  = hc >> 6;
  float4 s; s.x = s.y = s.z = s.w = 0.f;
  float d = 0.f;
  for (int sp = 0; sp < S; ++sp) {
    float4 v = *(const float4*)(part + ((size_t)sp * NN + i) * 128 + hc);
    s.x += v.x; s.y += v.y; s.z += v.z; s.w += v.w;
    d += denp[((size_t)sp * NN + i) * 2 + h];
  }
  const float sc = 1.f / (d + 0.001f);
  float4 bv = *(const float4*)(bias + hc);
  float4 o;
  o.x = s.x * sc + bv.x;
  o.y = s.y * sc + bv.y;
  o.z = s.z * sc + bv.z;
  o.w = s.w * sc + bv.w;
  *(float4*)(out + (size_t)i * 128 + hc) = o;
}

extern "C" void kernel_launch(void* const* d_in, const int* in_sizes, int n_in,
                              void* d_out, int out_size, void* d_ws, size_t ws_size,
                              hipStream_t stream) {
  const float* A    = (const float*)d_in[0];
  const float* X    = (const float*)d_in[1];
  const float* W    = (const float*)d_in[2];
  const float* attn = (const float*)d_in[3];
  const float* bias = (const float*)d_in[4];
  float* out = (float*)d_out;

  char* ws = (char*)d_ws;
  size_t off = 0;
  ushort_t* XpT = (ushort_t*)(ws + off); off += (size_t)128 * NN * sizeof(ushort_t); // 2 MB
  float* x0g = (float*)(ws + off); off += (size_t)NN * 2 * sizeof(float);
  float* x1g = (float*)(ws + off); off += (size_t)2 * NN * sizeof(float);

  // k-split: prefer 4 (4 blocks/CU); degrade if ws is small
  int S = 4;
  while (S > 1) {
    size_t need = off + (size_t)S * NN * 2 * 4 + (size_t)S * NN * 128 * 4;
    if (need <= ws_size) break;
    S >>= 1;
  }
  float* denp = (float*)(ws + off); off += (size_t)S * NN * 2 * sizeof(float);
  float* part = (float*)(ws + off);
  const int KS = NN / S;

  k1_project<<<256, 256, 0, stream>>>(X, W, attn, XpT, x0g, x1g);
  k2_main<<<256 * S, 256, 0, stream>>>(A, XpT, x0g, x1g, part, denp, S, KS);
  k3_finish<<<1024, 256, 0, stream>>>(part, denp, bias, out, S);
}

// Round 3
// 101.524 us; speedup vs baseline: 2.2421x; 2.2421x over previous
//
#include <hip/hip_runtime.h>
#include <hip/hip_bf16.h>

typedef unsigned short ushort_t;
typedef unsigned int uint_t;
using f32x4  = __attribute__((ext_vector_type(4))) float;
using short8 = __attribute__((ext_vector_type(8))) short;

#define NN 8192

__device__ __forceinline__ ushort_t f2bf(float f) {
  uint_t u = __builtin_bit_cast(uint_t, f);
  u += 0x7FFFu + ((u >> 16) & 1u);   // RNE
  return (ushort_t)(u >> 16);
}

__device__ __forceinline__ void gload16(const void* g, void* l) {
  __builtin_amdgcn_global_load_lds(
      (const __attribute__((address_space(1))) void*)g,
      (__attribute__((address_space(3))) void*)l, 16, 0, 0);
}

// ---------------------------------------------------------------------------
// K1: Xp = X @ W  -> XpT bf16 [2*64][8192] (row = h*64+c), x0[N][2], x1T[2][N]
// ---------------------------------------------------------------------------
__global__ __launch_bounds__(256, 2) void k1_project(
    const float* __restrict__ X, const float* __restrict__ W,
    const float* __restrict__ attn,
    ushort_t* __restrict__ XpT, float* __restrict__ x0g, float* __restrict__ x1g)
{
  __shared__ float    Xl[32][128];      // 16 KB
  __shared__ ushort_t XpL[128][56];     // 14 KB
  __shared__ float    P0[128][33];
  __shared__ float    P1[128][33];
  const int t  = threadIdx.x;
  const int nb = blockIdx.x * 32;

  #pragma unroll
  for (int r = 0; r < 4; ++r) {
    int chunk = r * 256 + t;
    ((float4*)(&Xl[0][0]))[chunk] = ((const float4*)(X + (size_t)nb * 128))[chunk];
  }
  __syncthreads();

  const int p = t & 127;
  const int g = t >> 7;
  const int h = p & 1, c = p >> 1;

  float acc[16];
  #pragma unroll
  for (int n = 0; n < 16; ++n) acc[n] = 0.f;

  for (int jc = 0; jc < 4; ++jc) {
    float wreg[32];
    #pragma unroll
    for (int jj = 0; jj < 32; ++jj) wreg[jj] = W[(jc * 32 + jj) * 128 + p];
    #pragma unroll
    for (int n = 0; n < 16; ++n) {
      const float4* xr = (const float4*)(&Xl[g * 16 + n][jc * 32]);
      float s = acc[n];
      #pragma unroll
      for (int q = 0; q < 8; ++q) {
        float4 xv = xr[q];
        s += xv.x * wreg[q*4+0] + xv.y * wreg[q*4+1] + xv.z * wreg[q*4+2] + xv.w * wreg[q*4+3];
      }
      acc[n] = s;
    }
  }

  const float a0 = attn[p];
  const float a1 = attn[128 + p];
  const int   row = h * 64 + c;
  #pragma unroll
  for (int n = 0; n < 16; ++n) {
    P0[p][g * 16 + n]  = acc[n] * a0;
    P1[p][g * 16 + n]  = acc[n] * a1;
    XpL[row][g * 16 + n] = f2bf(acc[n]);
  }
  __syncthreads();

  if (t < 128) {
    ushort_t* dst = XpT + (size_t)t * NN + nb;
    const uint4* src = (const uint4*)(&XpL[t][0]);
    ((uint4*)dst)[0] = src[0];
    ((uint4*)dst)[1] = src[1];
    ((uint4*)dst)[2] = src[2];
    ((uint4*)dst)[3] = src[3];
  }
  if (t < 64) {
    int node = t >> 1, hh = t & 1;
    float s0 = 0.f, s1 = 0.f;
    #pragma unroll
    for (int cc = 0; cc < 64; ++cc) {
      s0 += P0[cc * 2 + hh][node];
      s1 += P1[cc * 2 + hh][node];
    }
    x0g[(nb + node) * 2 + hh] = s0;
    x1g[hh * NN + nb + node]  = s1;
  }
}

// ---------------------------------------------------------------------------
// K2: pipelined. A/x1 reg-prefetch 1 tile ahead; Xp tile via global_load_lds
// (pre-swizzled source) into double-buffered LDS; raw s_barrier + vmcnt(8).
// ---------------------------------------------------------------------------
__global__ __launch_bounds__(256, 4) void k2_main(
    const float* __restrict__ A, const ushort_t* __restrict__ XpT,
    const float* __restrict__ x0g, const float* __restrict__ x1g,
    float* __restrict__ part, float* __restrict__ denp,
    const int S, const int KS)
{
  __shared__ __align__(16) ushort_t Pl[64 * 64];        // 8 KB
  __shared__ __align__(16) ushort_t Bl[2 * 128 * 64];   // 32 KB double buffer
  const int t  = threadIdx.x;
  const int b  = blockIdx.x;
  const int rb = b / S, sp = b % S;
  const int ib = rb * 32;
  const int k0 = sp * KS;
  const int lane = t & 63, w = t >> 6;
  const int hw = w & 1, iw = (w >> 1) * 16;
  const int pr = t >> 4;
  const int pk = (t & 15) * 4;

  float x0a[2][2];
  #pragma unroll
  for (int ps = 0; ps < 2; ++ps) {
    float2 v = *(const float2*)(x0g + (ib + ps * 16 + pr) * 2);
    x0a[ps][0] = v.x; x0a[ps][1] = v.y;
  }

  // B-stage addressing: chunk c = q*256+t -> LDS linear c*16B; source granule
  // inverse-swizzled so swizzled reads (byte ^ ((row&7)<<4)) see linear data.
  int srcOff[4], ldsOff[4];
  #pragma unroll
  for (int q = 0; q < 4; ++q) {
    int c = q * 256 + t;
    int cr = c >> 3, j = c & 7;
    srcOff[q] = cr * NN + ((j ^ (cr & 7)) << 3);  // elements
    ldsOff[q] = (q * 256 + w * 64) << 3;          // elements, wave-uniform
  }

  // Pl write byte offsets
  int plw[2][2];
  #pragma unroll
  for (int ps = 0; ps < 2; ++ps)
    #pragma unroll
    for (int hh = 0; hh < 2; ++hh) {
      int row = hh * 32 + ps * 16 + pr;
      plw[ps][hh] = (row * 128 + pk * 2) ^ ((pr & 7) << 4);
    }

  // MFMA read byte offsets
  int aoff[2], boff[2][4];
  const int arow = hw * 32 + iw + (lane & 15);
  #pragma unroll
  for (int ks = 0; ks < 2; ++ks) {
    aoff[ks] = (arow * 128 + ks * 64 + (lane >> 4) * 16) ^ ((arow & 7) << 4);
    #pragma unroll
    for (int cb = 0; cb < 4; ++cb) {
      int brow = hw * 64 + cb * 16 + (lane & 15);
      boff[ks][cb] = (brow * 128 + ks * 64 + (lane >> 4) * 16) ^ ((brow & 7) << 4);
    }
  }

  f32x4 acc[4] = {};
  float den[2][2] = {};

  const float* Ap0 = A + (size_t)(ib + pr) * NN + k0 + pk;
  const float* Ap1 = A + (size_t)(ib + 16 + pr) * NN + k0 + pk;
  const float* Xq0 = x1g + k0 + pk;
  const float* Xq1 = x1g + NN + k0 + pk;
  const int nt = KS >> 6;

  // --- prologue: cur regs + B(0) ---
  float4 aC0 = *(const float4*)(Ap0);
  float4 aC1 = *(const float4*)(Ap1);
  float4 xC0 = *(const float4*)(Xq0);
  float4 xC1 = *(const float4*)(Xq1);
  {
    const ushort_t* s = XpT + k0;
    #pragma unroll
    for (int q = 0; q < 4; ++q) gload16(s + srcOff[q], Bl + ldsOff[q]);
  }
  float4 aN0 = aC0, aN1 = aC1, xN0 = xC0, xN1 = xC1;

  for (int tt = 0; tt < nt; ++tt) {
    const int kt = k0 + (tt << 6);
    const int par = tt & 1;
    const bool pf = (tt + 1 < nt);

    // prefetch next A / x1 into regs (4 vmem ops)
    if (pf) {
      aN0 = *(const float4*)(Ap0 + (tt + 1) * 64);
      aN1 = *(const float4*)(Ap1 + (tt + 1) * 64);
      xN0 = *(const float4*)(Xq0 + (tt + 1) * 64);
      xN1 = *(const float4*)(Xq1 + (tt + 1) * 64);
    }

    // ---- P compute (VALU) from cur regs ----
    float aarr[2][4] = {{aC0.x, aC0.y, aC0.z, aC0.w}, {aC1.x, aC1.y, aC1.z, aC1.w}};
    float xarr[2][4] = {{xC0.x, xC0.y, xC0.z, xC0.w}, {xC1.x, xC1.y, xC1.z, xC1.w}};
    uint_t pp[2][2][2];
    #pragma unroll
    for (int ps = 0; ps < 2; ++ps) {
      #pragma unroll
      for (int hh = 0; hh < 2; ++hh) {
        ushort_t bf[4];
        #pragma unroll
        for (int j = 0; j < 4; ++j) {
          float s   = x0a[ps][hh] + xarr[hh][j];
          float lrl = fmaxf(s, 0.2f * s);
          float e   = __expf(lrl);
          float pv  = aarr[ps][j] * e;
          den[ps][hh] += pv;
          bf[j] = f2bf(pv);
        }
        pp[ps][hh][0] = (uint_t)bf[0] | ((uint_t)bf[1] << 16);
        pp[ps][hh][1] = (uint_t)bf[2] | ((uint_t)bf[3] << 16);
      }
    }

    // ---- barrier A: everyone done reading Pl(t-1) and Bl[par^1] ----
    asm volatile("s_waitcnt lgkmcnt(0)" ::: "memory");
    __builtin_amdgcn_s_barrier();
    asm volatile("" ::: "memory");

    // stage B(t+1) into the buffer MFMA(t) does not read (4 vmem ops)
    if (pf) {
      const ushort_t* s = XpT + kt + 64;
      ushort_t* d = Bl + (par ^ 1) * 8192;
      #pragma unroll
      for (int q = 0; q < 4; ++q) gload16(s + srcOff[q], d + ldsOff[q]);
    }

    // write Pl(t)
    #pragma unroll
    for (int ps = 0; ps < 2; ++ps) {
      #pragma unroll
      for (int hh = 0; hh < 2; ++hh) {
        uint2 v; v.x = pp[ps][hh][0]; v.y = pp[ps][hh][1];
        *(uint2*)((char*)Pl + plw[ps][hh]) = v;
      }
    }

    // ---- barrier B: Pl(t) written; B(t) landed (allow 8 newest in flight) ----
    if (pf) asm volatile("s_waitcnt vmcnt(8) lgkmcnt(0)" ::: "memory");
    else    asm volatile("s_waitcnt vmcnt(0) lgkmcnt(0)" ::: "memory");
    __builtin_amdgcn_s_barrier();
    asm volatile("" ::: "memory");

    // ---- MFMA on tile t ----
    const char* BlC = (const char*)(Bl + par * 8192);
    #pragma unroll
    for (int ks = 0; ks < 2; ++ks) {
      short8 af = *(const short8*)((const char*)Pl + aoff[ks]);
      #pragma unroll
      for (int cb = 0; cb < 4; ++cb) {
        short8 bv = *(const short8*)(BlC + boff[ks][cb]);
        acc[cb] = __builtin_amdgcn_mfma_f32_16x16x32_bf16(af, bv, acc[cb], 0, 0, 0);
      }
    }

    if (pf) { aC0 = aN0; aC1 = aN1; xC0 = xN0; xC1 = xN1; }
  }

  // --- den: reduce across 16-lane groups ---
  #pragma unroll
  for (int ps = 0; ps < 2; ++ps) {
    #pragma unroll
    for (int hh = 0; hh < 2; ++hh) {
      float d = den[ps][hh];
      d += __shfl_xor(d, 1, 16);
      d += __shfl_xor(d, 2, 16);
      d += __shfl_xor(d, 4, 16);
      d += __shfl_xor(d, 8, 16);
      if ((t & 15) == 0)
        denp[((size_t)sp * NN + ib + ps * 16 + (t >> 4)) * 2 + hh] = d;
    }
  }

  // --- partial numerators (C/D layout: col=lane&15, row=(lane>>4)*4+r) ---
  float* pbase = part + ((size_t)sp * NN + ib) * 128;
  #pragma unroll
  for (int cb = 0; cb < 4; ++cb) {
    #pragma unroll
    for (int r = 0; r < 4; ++r) {
      int lr  = iw + (lane >> 4) * 4 + r;
      int col = cb * 16 + (lane & 15);
      pbase[lr * 128 + hw * 64 + col] = acc[cb][r];
    }
  }
}

// ---------------------------------------------------------------------------
// K3: combine splits, normalize, add bias.
// ---------------------------------------------------------------------------
__global__ __launch_bounds__(256) void k3_finish(
    const float* __restrict__ part, const float* __restrict__ denp,
    const float* __restrict__ bias, float* __restrict__ out, const int S)
{
  const int idx = blockIdx.x * 256 + threadIdx.x;
  const int i  = idx >> 5;
  const int hc = (idx & 31) * 4;
  const int h  = hc >> 6;
  float4 s; s.x = s.y = s.z = s.w = 0.f;
  float d = 0.f;
  for (int sp = 0; sp < S; ++sp) {
    float4 v = *(const float4*)(part + ((size_t)sp * NN + i) * 128 + hc);
    s.x += v.x; s.y += v.y; s.z += v.z; s.w += v.w;
    d += denp[((size_t)sp * NN + i) * 2 + h];
  }
  const float sc = 1.f / (d + 0.001f);
  float4 bv = *(const float4*)(bias + hc);
  float4 o;
  o.x = s.x * sc + bv.x;
  o.y = s.y * sc + bv.y;
  o.z = s.z * sc + bv.z;
  o.w = s.w * sc + bv.w;
  *(float4*)(out + (size_t)i * 128 + hc) = o;
}

extern "C" void kernel_launch(void* const* d_in, const int* in_sizes, int n_in,
                              void* d_out, int out_size, void* d_ws, size_t ws_size,
                              hipStream_t stream) {
  const float* A    = (const float*)d_in[0];
  const float* X    = (const float*)d_in[1];
  const float* W    = (const float*)d_in[2];
  const float* attn = (const float*)d_in[3];
  const float* bias = (const float*)d_in[4];
  float* out = (float*)d_out;

  char* ws = (char*)d_ws;
  size_t off = 0;
  ushort_t* XpT = (ushort_t*)(ws + off); off += (size_t)128 * NN * sizeof(ushort_t);
  float* x0g = (float*)(ws + off); off += (size_t)NN * 2 * sizeof(float);
  float* x1g = (float*)(ws + off); off += (size_t)2 * NN * sizeof(float);

  int S = 4;
  while (S > 1) {
    size_t need = off + (size_t)S * NN * 2 * 4 + (size_t)S * NN * 128 * 4;
    if (need <= ws_size) break;
    S >>= 1;
  }
  float* denp = (float*)(ws + off); off += (size_t)S * NN * 2 * sizeof(float);
  float* part = (float*)(ws + off);
  const int KS = NN / S;

  k1_project<<<256, 256, 0, stream>>>(X, W, attn, XpT, x0g, x1g);
  k2_main<<<256 * S, 256, 0, stream>>>(A, XpT, x0g, x1g, part, denp, S, KS);
  k3_finish<<<1024, 256, 0, stream>>>(part, denp, bias, out, S);
}